// Round 5
// baseline (288.730 us; speedup 1.0000x reference)
//
#include <hip/hip_runtime.h>
#include <hip/hip_bf16.h>
#include <stdint.h>

#define NROWS   65536
#define RPB     64
#define NBLK    (NROWS/RPB)       // 1024
#define H2N     100
#define KPAD    128
#define N3      1224
#define OUTW    2193
#define NMAIN   77                // main n-tiles (1232 cols padded)
#define NPAIR   61                // pair tiles per side (976 cols padded)
#define T1OFF   77                // tiles holding h3[c1[p]]
#define T2OFF   138               // tiles holding h3[c2[p]]
#define NTOT    199               // total tiles
#define TAILN   969

typedef __attribute__((ext_vector_type(8))) short bf16x8;
typedef __attribute__((ext_vector_type(4))) float f32x4;

__device__ __forceinline__ float fast_sigmoid(float z){
    return __builtin_amdgcn_rcpf(1.0f + __expf(-z));
}
__device__ __forceinline__ unsigned short f2bf(float v){
    __hip_bfloat16 h = __float2bfloat16(v);
    return *reinterpret_cast<unsigned short*>(&h);
}
// 16B store; out rows only 4B-aligned (OUTW=2193): memcpy keeps dwordx4 w/o align assert
__device__ __forceinline__ void store16(float* p, f32x4 v){
    __builtin_memcpy(p, &v, 16);
}

// Build fragment-ordered extended B: w3f[((t*4+ks)*64+lane)*8 + e]
//   = bf16( W3[k=ks*32+(lane>>4)*8+e][ srccol(t, lane&15) ] ), zero-padded.
__global__ void prep_kernel(const float* __restrict__ W3,
                            const float* __restrict__ b3,
                            const float* __restrict__ wgt,
                            const int* __restrict__ idx1,
                            const int* __restrict__ idx2,
                            unsigned short* __restrict__ w3f,
                            float* __restrict__ b3f,
                            float* __restrict__ pwf){
    const int t    = blockIdx.x;            // one tile per block
    const int ks   = threadIdx.x >> 6;
    const int lane = threadIdx.x & 63;
    const int lm   = lane & 15, lg = lane >> 4;

    int col = -1;
    if (t < T1OFF){
        int c = t * 16 + lm;
        if (c < N3) col = c;
    } else if (t < T2OFF){
        int p = (t - T1OFF) * 16 + lm;
        if (p < TAILN){ int j = p / 17; col = idx1[j] * 17 + (p - j * 17); }
    } else {
        int p = (t - T2OFF) * 16 + lm;
        if (p < TAILN){ int j = p / 17; col = idx2[j] * 17 + (p - j * 17); }
    }

    unsigned short vals[8];
    #pragma unroll
    for (int e = 0; e < 8; ++e){
        int k = ks * 32 + lg * 8 + e;
        float v = (col >= 0 && k < H2N) ? W3[k * N3 + col] : 0.0f;
        vals[e] = f2bf(v);
    }
    *reinterpret_cast<bf16x8*>(w3f + ((size_t)(t * 4 + ks) * 64 + lane) * 8)
        = *reinterpret_cast<bf16x8*>(vals);

    if (ks == 0 && lg == 0)
        b3f[t * 16 + lm] = (col >= 0) ? b3[col] : 0.0f;
    if (ks == 0 && lg == 1 && t >= T1OFF && t < T2OFF){
        int p = (t - T1OFF) * 16 + lm;
        if (p < TAILN) pwf[p] = wgt[p / 17];
    }
}

__global__ __launch_bounds__(256, 3)
void snn_kernel(const float* __restrict__ x,
                const float* __restrict__ W1, const float* __restrict__ b1,
                const float* __restrict__ W2, const float* __restrict__ b2,
                const unsigned short* __restrict__ w3f,
                const float* __restrict__ b3f,
                const float* __restrict__ pwf,
                float* __restrict__ out)
{
    __shared__ __align__(16) unsigned short lds_h2[RPB][KPAD];   // 16 KB
    __shared__ float lds_h1[RPB][10];

    const int t    = threadIdx.x;
    const int row0 = blockIdx.x * RPB;

    // ---- layer 1
    for (int i = t; i < RPB * 10; i += 256){
        int r = i / 10, j = i - r * 10;
        lds_h1[r][j] = fast_sigmoid(x[row0 + r] * W1[j] + b1[j]);
    }
    __syncthreads();

    // ---- layer 2 -> bf16 LDS
    for (int i = t; i < RPB * KPAD; i += 256){
        int r = i >> 7, c = i & 127;
        float v = 0.0f;
        if (c < H2N){
            float z = b2[c];
            #pragma unroll
            for (int j = 0; j < 10; ++j) z += lds_h1[r][j] * W2[j * H2N + c];
            v = fast_sigmoid(z);
        }
        lds_h2[r][c] = f2bf(v);
    }
    __syncthreads();

    // ---- layer 3 + tail: A = W3-tile (rows = out cols), B = h2 (cols = out rows)
    // D: out row = row0 + rt*16 + (lane&15); out col = tile*16 + (lane>>4)*4 + reg
    const int lane = t & 63, wid = t >> 6;
    const int lm = lane & 15, lg = lane >> 4;

    bf16x8 hfr[4][4];   // h2 fragments (B operand), 4 row-tiles x 4 k-steps = 64 VGPR
    #pragma unroll
    for (int rt = 0; rt < 4; ++rt)
        #pragma unroll
        for (int ks = 0; ks < 4; ++ks)
            hfr[rt][ks] = *reinterpret_cast<const bf16x8*>(&lds_h2[rt * 16 + lm][ks * 32 + lg * 8]);

    unsigned int rrow[4];   // 32-bit element offsets (out < 1.5e8 elements)
    #pragma unroll
    for (int rt = 0; rt < 4; ++rt)
        rrow[rt] = (unsigned int)(row0 + rt * 16 + lm) * OUTW;

    #define LOADFRAG(dst, tile) do {                                              \
        const unsigned short* bp_ = w3f + ((size_t)((tile) * 4) * 64 + lane) * 8; \
        _Pragma("unroll")                                                         \
        for (int ks_ = 0; ks_ < 4; ++ks_)                                         \
            dst[ks_] = *reinterpret_cast<const bf16x8*>(bp_ + (size_t)ks_ * 512); \
    } while(0)

    // ===== main tiles: cols 0..1223, double-buffered W3 frags + b3 =====
    {
        bf16x8 cw[4], nw[4];
        f32x4 b3c = {0,0,0,0}, b3n;
        if (wid < NMAIN){
            LOADFRAG(cw, wid);
            b3c = *reinterpret_cast<const f32x4*>(b3f + wid * 16 + lg * 4);
        }
        for (int nt = wid; nt < NMAIN; nt += 4){
            const int ntn = nt + 4;
            if (ntn < NMAIN){
                LOADFRAG(nw, ntn);
                b3n = *reinterpret_cast<const f32x4*>(b3f + ntn * 16 + lg * 4);
            }

            f32x4 a[4] = {{0,0,0,0},{0,0,0,0},{0,0,0,0},{0,0,0,0}};
            #pragma unroll
            for (int ks = 0; ks < 4; ++ks)
                #pragma unroll
                for (int rt = 0; rt < 4; ++rt)
                    a[rt] = __builtin_amdgcn_mfma_f32_16x16x32_bf16(cw[ks], hfr[rt][ks], a[rt], 0, 0, 0);

            const int cb = nt * 16 + lg * 4;
            if (cb + 3 < N3){
                #pragma unroll
                for (int rt = 0; rt < 4; ++rt){
                    f32x4 v;
                    #pragma unroll
                    for (int r = 0; r < 4; ++r) v[r] = fast_sigmoid(a[rt][r] + b3c[r]);
                    store16(out + rrow[rt] + cb, v);
                }
            } else if (cb < N3){
                #pragma unroll
                for (int rt = 0; rt < 4; ++rt)
                    #pragma unroll
                    for (int r = 0; r < 4; ++r)
                        if (cb + r < N3)
                            out[rrow[rt] + cb + r] = fast_sigmoid(a[rt][r] + b3c[r]);
            }
            if (ntn < NMAIN){
                #pragma unroll
                for (int ks = 0; ks < 4; ++ks) cw[ks] = nw[ks];
                b3c = b3n;
            }
        }
    }

    // ===== pair tiles: tail = w*sig(u1) + (1-w)*sig(u2) =====
    {
        bf16x8 c1f[4], n1f[4];
        if (wid < NPAIR) LOADFRAG(c1f, T1OFF + wid);
        for (int i = wid; i < NPAIR; i += 4){
            bf16x8 c2f[4];
            LOADFRAG(c2f, T2OFF + i);
            const int inext = i + 4;
            if (inext < NPAIR) LOADFRAG(n1f, T1OFF + inext);

            f32x4 a1[4] = {{0,0,0,0},{0,0,0,0},{0,0,0,0},{0,0,0,0}};
            f32x4 a2[4] = {{0,0,0,0},{0,0,0,0},{0,0,0,0},{0,0,0,0}};
            #pragma unroll
            for (int ks = 0; ks < 4; ++ks)
                #pragma unroll
                for (int rt = 0; rt < 4; ++rt)
                    a1[rt] = __builtin_amdgcn_mfma_f32_16x16x32_bf16(c1f[ks], hfr[rt][ks], a1[rt], 0, 0, 0);
            #pragma unroll
            for (int ks = 0; ks < 4; ++ks)
                #pragma unroll
                for (int rt = 0; rt < 4; ++rt)
                    a2[rt] = __builtin_amdgcn_mfma_f32_16x16x32_bf16(c2f[ks], hfr[rt][ks], a2[rt], 0, 0, 0);

            const int pb = i * 16 + lg * 4;
            const f32x4 bv1 = *reinterpret_cast<const f32x4*>(b3f + (T1OFF + i) * 16 + lg * 4);
            const f32x4 bv2 = *reinterpret_cast<const f32x4*>(b3f + (T2OFF + i) * 16 + lg * 4);
            if (pb + 3 < TAILN){
                const f32x4 wv = *reinterpret_cast<const f32x4*>(pwf + pb);
                #pragma unroll
                for (int rt = 0; rt < 4; ++rt){
                    f32x4 v;
                    #pragma unroll
                    for (int r = 0; r < 4; ++r){
                        float u1 = fast_sigmoid(a1[rt][r] + bv1[r]);
                        float u2 = fast_sigmoid(a2[rt][r] + bv2[r]);
                        v[r] = fmaf(wv[r], u1 - u2, u2);
                    }
                    store16(out + rrow[rt] + N3 + pb, v);
                }
            } else if (pb < TAILN){
                #pragma unroll
                for (int r = 0; r < 4; ++r){
                    const int p = pb + r;
                    if (p < TAILN){
                        const float wvs = pwf[p];
                        #pragma unroll
                        for (int rt = 0; rt < 4; ++rt){
                            float u1 = fast_sigmoid(a1[rt][r] + bv1[r]);
                            float u2 = fast_sigmoid(a2[rt][r] + bv2[r]);
                            out[rrow[rt] + N3 + p] = fmaf(wvs, u1 - u2, u2);
                        }
                    }
                }
            }
            if (inext < NPAIR){
                #pragma unroll
                for (int ks = 0; ks < 4; ++ks) c1f[ks] = n1f[ks];
            }
        }
    }
    #undef LOADFRAG
}

extern "C" void kernel_launch(void* const* d_in, const int* in_sizes, int n_in,
                              void* d_out, int out_size, void* d_ws, size_t ws_size,
                              hipStream_t stream)
{
    const float* x   = (const float*)d_in[0];
    const float* W1  = (const float*)d_in[1];
    const float* b1  = (const float*)d_in[2];
    const float* W2  = (const float*)d_in[3];
    const float* b2  = (const float*)d_in[4];
    const float* W3  = (const float*)d_in[5];
    const float* b3  = (const float*)d_in[6];
    const float* wgt = (const float*)d_in[7];
    const int*   i1  = (const int*)d_in[8];
    const int*   i2  = (const int*)d_in[9];
    float* out = (float*)d_out;

    unsigned char* ws = (unsigned char*)d_ws;
    unsigned short* w3f = (unsigned short*)ws;                 // 199*4*64*8*2 = 815,104 B
    float*          b3f = (float*)(ws + 815104);               // 3184*4 = 12,736 B
    float*          pwf = (float*)(ws + 815104 + 12736);       // 976*4  =  3,904 B

    prep_kernel<<<NTOT, 256, 0, stream>>>(W3, b3, wgt, i1, i2, w3f, b3f, pwf);
    snn_kernel<<<NBLK, 256, 0, stream>>>(x, W1, b1, W2, b2, w3f, b3f, pwf, out);
}